// Round 8
// baseline (158.348 us; speedup 1.0000x reference)
//
#include <hip/hip_runtime.h>
#include <hip/hip_bf16.h>
#include <math.h>

#define BATCH 16
#define SEQ   2048
#define HID   128
#define DIM   64

typedef __attribute__((ext_vector_type(8))) short bf16x8;
typedef __attribute__((ext_vector_type(4))) float f32x4;

// 0.125 (1/sqrt(D)) * log2(e): folded into Wq so MFMA emits log2-domain scores
#define QSCALE 0.18033688011112042f
#define C0_PE  0.07195578314043169f   // ln(10000)/128

static __device__ __forceinline__ ushort f2bf(float f) {
    union { float f; unsigned u; } v; v.f = f;
    unsigned r = v.u + 0x7FFFu + ((v.u >> 16) & 1u);   // RNE
    return (ushort)(r >> 16);
}

static __device__ __forceinline__ float fast_exp2(float x) {
#if __has_builtin(__builtin_amdgcn_exp2f)
    return __builtin_amdgcn_exp2f(x);
#else
    return exp2f(x);
#endif
}

// ---------------------------------------------------------------------------
// PE table: pet[pos][h], fp32, 2048 x 128 (1 MB)   [R5-proven]
// ---------------------------------------------------------------------------
__global__ __launch_bounds__(256) void k_pe(float* __restrict__ pet) {
    int i = blockIdx.x * 256 + threadIdx.x;      // pair index, 2048*64 total
    int pos = i >> 6, hp = i & 63;
    float ang = (float)pos * __expf(-(float)(2 * hp) * C0_PE);
    pet[pos * HID + 2 * hp]     = __sinf(ang);
    pet[pos * HID + 2 * hp + 1] = __cosf(ang);
}

// ---------------------------------------------------------------------------
// Prep: wvf[h] = Wv[h,:]·Wf  and  Wt[outcol][k] = bf16([Wq*QSCALE | Wk]^T)
// [R4-proven]
// ---------------------------------------------------------------------------
__global__ void k_prep(const float* __restrict__ Wq, const float* __restrict__ Wk,
                       const float* __restrict__ Wv, const float* __restrict__ Wf,
                       ushort* __restrict__ Wt, float* __restrict__ wvf) {
    const int tid = threadIdx.x;
    if (tid < HID) {
        float s = 0.f;
        #pragma unroll 8
        for (int d = 0; d < DIM; ++d) s += Wv[tid * DIM + d] * Wf[d];
        wvf[tid] = s;
    }
    for (int i = tid; i < 128 * 128; i += 256) {
        int col = i >> 7, k = i & 127;
        float v = (col < 64) ? Wq[k * DIM + col] * QSCALE : Wk[k * DIM + (col - 64)];
        Wt[i] = f2bf(v);
    }
}

// ---------------------------------------------------------------------------
// QKV (MFMA, no LDS, no trans): block = 64 rows, wave = 16 rows.
// af = x + pet (table loads only); A = Wt tile, B = af rows ->
// lane holds 4 consecutive DIM cols of ONE row -> 8-byte stores (R7 layout).
// ---------------------------------------------------------------------------
__global__ __launch_bounds__(256) void k_qkv(
    const float* __restrict__ x, const float* __restrict__ pet,
    const ushort* __restrict__ Wt, const float* __restrict__ wvf,
    ushort* __restrict__ Qb, ushort* __restrict__ Kb, float* __restrict__ vf)
{
    const int tid  = threadIdx.x;
    const int wave = tid >> 6;
    const int lane = tid & 63;
    const int quad = lane >> 4;
    const int col  = lane & 15;
    const int rowbase = blockIdx.x * 64 + wave * 16;
    const int grow = rowbase + col;          // this lane's xp row
    const int pos  = grow & (SEQ - 1);

    // ---- build xp fragments (B-side) + vf partial ----
    bf16x8 af[4];
    float vpart = 0.f;
    #pragma unroll
    for (int c = 0; c < 4; ++c) {
        const float* xp = x   + (size_t)grow * HID + quad * 8 + c * 32;
        const float* pp = pet + (size_t)pos  * HID + quad * 8 + c * 32;
        float4 v0 = *(const float4*)(xp);
        float4 v1 = *(const float4*)(xp + 4);
        float4 p0 = *(const float4*)(pp);
        float4 p1 = *(const float4*)(pp + 4);
        float t[8] = {v0.x + p0.x, v0.y + p0.y, v0.z + p0.z, v0.w + p0.w,
                      v1.x + p1.x, v1.y + p1.y, v1.z + p1.z, v1.w + p1.w};
        const float* wp = wvf + quad * 8 + c * 32;
        float4 w0 = *(const float4*)(wp);
        float4 w1 = *(const float4*)(wp + 4);
        vpart += t[0] * w0.x + t[1] * w0.y + t[2] * w0.z + t[3] * w0.w +
                 t[4] * w1.x + t[5] * w1.y + t[6] * w1.z + t[7] * w1.w;
        short* ap = (short*)&af[c];
        #pragma unroll
        for (int j = 0; j < 8; ++j) ap[j] = (short)f2bf(t[j]);
    }

    vpart += __shfl_xor(vpart, 16);
    vpart += __shfl_xor(vpart, 32);
    if (quad == 0) vf[grow] = vpart;

    // ---- 8 outcol tiles: 0..3 -> Q (prescaled), 4..7 -> K ----
    #pragma unroll
    for (int t = 0; t < 8; ++t) {
        const ushort* wrow = Wt + (size_t)(t * 16 + col) * 128 + quad * 8;
        f32x4 acc = {0.f, 0.f, 0.f, 0.f};
        #pragma unroll
        for (int c = 0; c < 4; ++c) {
            bf16x8 wfr = *(const bf16x8*)(wrow + c * 32);
            acc = __builtin_amdgcn_mfma_f32_16x16x32_bf16(wfr, af[c], acc, 0, 0, 0);
        }
        // D: row(quad*4+r) = outcol-in-tile, col(lane&15) = xp row
        ushort4 o = {f2bf(acc.x), f2bf(acc.y), f2bf(acc.z), f2bf(acc.w)};
        ushort* dst = (t < 4) ? Qb : Kb;
        *(ushort4*)&dst[(size_t)grow * DIM + (t & 3) * 16 + quad * 4] = o;
    }
}

// ---------------------------------------------------------------------------
// Stats (MFMA, transposed orientation, q-split x4): block = (ktile, qchunk, b),
// 256 thr = 4 waves; wave sweeps 128 q rows.  Partial column sums ->
// LDS merge -> atomicAdd into lb (zeroed by memset).
// ---------------------------------------------------------------------------
__global__ __launch_bounds__(256) void k_stats(
    const ushort* __restrict__ Qb, const ushort* __restrict__ Kb,
    float* __restrict__ lb)
{
    const int kt   = blockIdx.x;
    const int qc   = blockIdx.y;
    const int b    = blockIdx.z;
    const int k0   = kt * 64;
    const int tid  = threadIdx.x;
    const int wave = tid >> 6;
    const int lane = tid & 63;
    const int quad = lane >> 4;
    const int col  = lane & 15;

    __shared__ float sl[4][64];

    // resident K fragments (A-side): 4 tiles x 2 chunks
    bf16x8 kf[4][2];
    {
        const ushort* Kbase = Kb + ((size_t)(b * SEQ + k0)) * DIM;
        #pragma unroll
        for (int t = 0; t < 4; ++t)
            #pragma unroll
            for (int c = 0; c < 2; ++c)
                kf[t][c] = *(const bf16x8*)(Kbase + (size_t)(t * 16 + col) * DIM + quad * 8 + c * 32);
    }

    float l[4][4] = {};
    const ushort* Qrow = Qb + ((size_t)(b * SEQ + qc * 512 + wave * 128 + col)) * DIM + quad * 8;
    for (int qi = 0; qi < 8; ++qi) {
        bf16x8 q0 = *(const bf16x8*)(Qrow);
        bf16x8 q1 = *(const bf16x8*)(Qrow + 32);
        Qrow += 16 * DIM;
        #pragma unroll
        for (int t = 0; t < 4; ++t) {
            f32x4 acc = {0.f, 0.f, 0.f, 0.f};
            acc = __builtin_amdgcn_mfma_f32_16x16x32_bf16(kf[t][0], q0, acc, 0, 0, 0);
            acc = __builtin_amdgcn_mfma_f32_16x16x32_bf16(kf[t][1], q1, acc, 0, 0, 0);
            #pragma unroll
            for (int r = 0; r < 4; ++r)
                l[t][r] += fast_exp2(acc[r]);
        }
    }

    // reduce over the 16 q-cols (low 4 lane bits), end-only
    #pragma unroll
    for (int t = 0; t < 4; ++t)
        #pragma unroll
        for (int r = 0; r < 4; ++r) {
            float v = l[t][r];
            v += __shfl_xor(v, 1); v += __shfl_xor(v, 2);
            v += __shfl_xor(v, 4); v += __shfl_xor(v, 8);
            l[t][r] = v;
        }
    if (col == 0) {
        #pragma unroll
        for (int t = 0; t < 4; ++t)
            #pragma unroll
            for (int r = 0; r < 4; ++r)
                sl[wave][t * 16 + quad * 4 + r] = l[t][r];
    }
    __syncthreads();
    if (tid < 64) {
        float s = sl[0][tid] + sl[1][tid] + sl[2][tid] + sl[3][tid];
        atomicAdd(&lb[(size_t)b * SEQ + k0 + tid], s);
    }
}

// ---------------------------------------------------------------------------
// Out (MFMA, transposed orientation, q-split x4): same grid as k_stats.
// wcol = vf/lb computed per block (lb complete via kernel boundary).
// rs per q accumulated in-register; 2 shuffles + 1 atomicAdd per q row.
// ---------------------------------------------------------------------------
__global__ __launch_bounds__(256) void k_out(
    const ushort* __restrict__ Qb, const ushort* __restrict__ Kb,
    const float* __restrict__ vf, const float* __restrict__ lb,
    const float* __restrict__ bfp, float* __restrict__ outp)
{
    const int kt   = blockIdx.x;
    const int qc   = blockIdx.y;
    const int b    = blockIdx.z;
    const int k0   = kt * 64;
    const int tid  = threadIdx.x;
    const int wave = tid >> 6;
    const int lane = tid & 63;
    const int quad = lane >> 4;
    const int col  = lane & 15;

    __shared__ float wcol[64];

    if (tid < 64) {
        size_t g = (size_t)b * SEQ + k0 + tid;
        wcol[tid] = vf[g] / lb[g];
    }

    // resident K fragments (A-side): 4 tiles x 2 chunks
    bf16x8 kf[4][2];
    {
        const ushort* Kbase = Kb + ((size_t)(b * SEQ + k0)) * DIM;
        #pragma unroll
        for (int t = 0; t < 4; ++t)
            #pragma unroll
            for (int c = 0; c < 2; ++c)
                kf[t][c] = *(const bf16x8*)(Kbase + (size_t)(t * 16 + col) * DIM + quad * 8 + c * 32);
    }
    __syncthreads();

    float wreg[4][4];
    #pragma unroll
    for (int t = 0; t < 4; ++t)
        #pragma unroll
        for (int r = 0; r < 4; ++r)
            wreg[t][r] = wcol[t * 16 + quad * 4 + r];

    const float bias = bfp[0] * (1.0f / (SEQ / 64));   // 32 ktile-blocks per out elem
    float* outb = outp + (size_t)b * SEQ;
    const int qbase = qc * 512 + wave * 128;
    const ushort* Qrow = Qb + ((size_t)(b * SEQ + qbase + col)) * DIM + quad * 8;

    for (int qi = 0; qi < 8; ++qi) {
        bf16x8 q0 = *(const bf16x8*)(Qrow);
        bf16x8 q1 = *(const bf16x8*)(Qrow + 32);
        Qrow += 16 * DIM;
        float rs = 0.f;
        #pragma unroll
        for (int t = 0; t < 4; ++t) {
            f32x4 acc = {0.f, 0.f, 0.f, 0.f};
            acc = __builtin_amdgcn_mfma_f32_16x16x32_bf16(kf[t][0], q0, acc, 0, 0, 0);
            acc = __builtin_amdgcn_mfma_f32_16x16x32_bf16(kf[t][1], q1, acc, 0, 0, 0);
            #pragma unroll
            for (int r = 0; r < 4; ++r)
                rs += fast_exp2(acc[r]) * wreg[t][r];
        }
        rs += __shfl_xor(rs, 16);
        rs += __shfl_xor(rs, 32);
        if (quad == 0)
            atomicAdd(&outb[qbase + qi * 16 + col], rs + bias);
    }
}

// ---------------------------------------------------------------------------
extern "C" void kernel_launch(void* const* d_in, const int* in_sizes, int n_in,
                              void* d_out, int out_size, void* d_ws, size_t ws_size,
                              hipStream_t stream) {
    (void)in_sizes; (void)n_in; (void)ws_size;
    const float* x  = (const float*)d_in[0];
    const float* Wq = (const float*)d_in[1];
    const float* Wk = (const float*)d_in[2];
    const float* Wv = (const float*)d_in[3];
    const float* Wf = (const float*)d_in[4];
    const float* bf = (const float*)d_in[5];
    float* outp = (float*)d_out;

    float*  wvf = (float*)d_ws;                                  // 256 floats
    float*  vf  = wvf + 256;                                     // B*S
    float*  lb  = vf + (size_t)BATCH * SEQ;                      // B*S
    float*  pet = lb + (size_t)BATCH * SEQ;                      // SEQ*HID
    ushort* Wt  = (ushort*)(pet + (size_t)SEQ * HID);            // 128*128
    ushort* Qb  = Wt + 128 * 128;                                // B*S*D bf16
    ushort* Kb  = Qb + (size_t)BATCH * SEQ * DIM;                // B*S*D bf16

    hipMemsetAsync(d_out, 0, (size_t)out_size * sizeof(float), stream);
    hipMemsetAsync(lb, 0, (size_t)BATCH * SEQ * sizeof(float), stream);
    k_pe<<<SEQ * (HID / 2) / 256, 256, 0, stream>>>(pet);
    k_prep<<<1, 256, 0, stream>>>(Wq, Wk, Wv, Wf, Wt, wvf);
    k_qkv<<<BATCH * SEQ / 64, 256, 0, stream>>>(x, pet, Wt, wvf, Qb, Kb, vf);
    k_stats<<<dim3(SEQ / 64, 4, BATCH), 256, 0, stream>>>(Qb, Kb, lb);
    k_out<<<dim3(SEQ / 64, 4, BATCH), 256, 0, stream>>>(Qb, Kb, vf, lb, bf, outp);
}

// Round 9
// 141.437 us; speedup vs baseline: 1.1196x; 1.1196x over previous
//
#include <hip/hip_runtime.h>
#include <hip/hip_bf16.h>
#include <math.h>

#define BATCH 16
#define SEQ   2048
#define HID   128
#define DIM   64
#define XSP   136   // LDS xs row pitch (ushorts): 272B -> bank shift 4/row, 2-way max

typedef __attribute__((ext_vector_type(8))) short bf16x8;
typedef __attribute__((ext_vector_type(4))) float f32x4;

// 0.125 (1/sqrt(D)) * log2(e): folded into Wq so MFMA emits log2-domain scores
#define QSCALE 0.18033688011112042f
#define C0_PE  0.07195578314043169f   // ln(10000)/128

static __device__ __forceinline__ ushort f2bf(float f) {
    union { float f; unsigned u; } v; v.f = f;
    unsigned r = v.u + 0x7FFFu + ((v.u >> 16) & 1u);   // RNE
    return (ushort)(r >> 16);
}

static __device__ __forceinline__ float fast_exp2(float x) {
#if __has_builtin(__builtin_amdgcn_exp2f)
    return __builtin_amdgcn_exp2f(x);
#else
    return exp2f(x);
#endif
}

// ---------------------------------------------------------------------------
// PE table + weight prep in ONE dispatch.
// Blocks 0..511: pet[pos][h] (fp32, 1 MB).  Last block additionally:
// wvf[h] = Wv[h,:]·Wf  and  Wt[outcol][k] = bf16([Wq*QSCALE | Wk]^T).
// ---------------------------------------------------------------------------
__global__ __launch_bounds__(256) void k_peprep(
    const float* __restrict__ Wq, const float* __restrict__ Wk,
    const float* __restrict__ Wv, const float* __restrict__ Wf,
    float* __restrict__ pet, ushort* __restrict__ Wt, float* __restrict__ wvf)
{
    const int tid = threadIdx.x;
    int i = blockIdx.x * 256 + tid;              // pair index, 2048*64 total
    int pos = i >> 6, hp = i & 63;
    float ang = (float)pos * __expf(-(float)(2 * hp) * C0_PE);
    pet[pos * HID + 2 * hp]     = __sinf(ang);
    pet[pos * HID + 2 * hp + 1] = __cosf(ang);

    if (blockIdx.x == gridDim.x - 1) {
        if (tid < HID) {
            float s = 0.f;
            #pragma unroll 8
            for (int d = 0; d < DIM; ++d) s += Wv[tid * DIM + d] * Wf[d];
            wvf[tid] = s;
        }
        for (int j = tid; j < 128 * 128; j += 256) {
            int col = j >> 7, k = j & 127;
            float v = (col < 64) ? Wq[k * DIM + col] * QSCALE : Wk[k * DIM + (col - 64)];
            Wt[j] = f2bf(v);
        }
    }
}

// ---------------------------------------------------------------------------
// QKV (LDS-staged, MFMA): 512 thr x 512 blocks; block = 64 rows.
// Stage 1 (coalesced): xs[64][128] = bf16(x + pet), vf partials (fp32).
// Stage 2: 8 waves = (rowgroup 0..3) x (half: 0=Q,1=K); per wave 4
//          ds_read_b128 frags + 16 MFMAs + 4 x 8B stores.
// Output layout identical to R7/R8: dst[row*DIM + tile*16 + quad*4 + r].
// ---------------------------------------------------------------------------
__global__ __launch_bounds__(512) void k_qkv(
    const float* __restrict__ x, const float* __restrict__ pet,
    const ushort* __restrict__ Wt, const float* __restrict__ wvf,
    ushort* __restrict__ Qb, ushort* __restrict__ Kb, float* __restrict__ vf)
{
    __shared__ ushort xs[64 * XSP];      // ~17.4 KB
    __shared__ float  vred[64][9];       // padded

    const int tid = threadIdx.x;

    // ---- Stage 1: coalesced load x+pet -> bf16 LDS, vf partial ----
    {
        const int srow = tid >> 3;               // 0..63
        const int soff = (tid & 7) * 16;         // 0..112
        const int growS = blockIdx.x * 64 + srow;
        const int posS  = growS & (SEQ - 1);
        const float4* x4 = (const float4*)(x   + (size_t)growS * HID + soff);
        const float4* p4 = (const float4*)(pet + (size_t)posS  * HID + soff);
        const float4* w4 = (const float4*)(wvf + soff);
        float vpart = 0.f;
        #pragma unroll
        for (int j = 0; j < 4; ++j) {
            float4 a = x4[j];
            float4 p = p4[j];
            float4 w = w4[j];
            float t0 = a.x + p.x, t1 = a.y + p.y, t2 = a.z + p.z, t3 = a.w + p.w;
            vpart += t0 * w.x + t1 * w.y + t2 * w.z + t3 * w.w;
            ushort4 o = {f2bf(t0), f2bf(t1), f2bf(t2), f2bf(t3)};
            *(ushort4*)&xs[srow * XSP + soff + j * 4] = o;
        }
        vred[srow][tid & 7] = vpart;
    }
    __syncthreads();

    if (tid < 64) {
        float s = 0.f;
        #pragma unroll
        for (int j = 0; j < 8; ++j) s += vred[tid][j];
        vf[blockIdx.x * 64 + tid] = s;
    }

    // ---- Stage 2: MFMA per wave ----
    const int wave = tid >> 6;
    const int lane = tid & 63;
    const int quad = lane >> 4;
    const int col  = lane & 15;
    const int rg   = wave & 3;           // row group (16 rows)
    const int half = wave >> 2;          // 0 = Q, 1 = K

    bf16x8 af[4];
    #pragma unroll
    for (int c = 0; c < 4; ++c)
        af[c] = *(const bf16x8*)&xs[(rg * 16 + col) * XSP + quad * 8 + c * 32];

    const int growW = blockIdx.x * 64 + rg * 16 + col;
    ushort* dst = half ? Kb : Qb;
    #pragma unroll
    for (int t = 0; t < 4; ++t) {
        const ushort* wrow = Wt + (size_t)((half * 4 + t) * 16 + col) * 128 + quad * 8;
        f32x4 acc = {0.f, 0.f, 0.f, 0.f};
        #pragma unroll
        for (int c = 0; c < 4; ++c) {
            bf16x8 wfr = *(const bf16x8*)(wrow + c * 32);
            acc = __builtin_amdgcn_mfma_f32_16x16x32_bf16(wfr, af[c], acc, 0, 0, 0);
        }
        // D: row(quad*4+r) = outcol-in-tile, col(lane&15) = xp row
        ushort4 o = {f2bf(acc.x), f2bf(acc.y), f2bf(acc.z), f2bf(acc.w)};
        *(ushort4*)&dst[(size_t)growW * DIM + t * 16 + quad * 4] = o;
    }
}

// ---------------------------------------------------------------------------
// Fused attention (MFMA, R7-verified, 51 us measured): block = (b, 64 k-cols),
// 512 thr = 8 waves.  A = K-frag (m = k), B = Q rows (n = q).
// Phase A: l[t][r] reg-accumulate exp2 over q; end-only reduction.
// Phase B: rs accumulates exp2*w; 2 shuffles + 1 atomicAdd per q row.
// ---------------------------------------------------------------------------
__global__ __launch_bounds__(512) void k_attn(
    const ushort* __restrict__ Qb, const ushort* __restrict__ Kb,
    const float* __restrict__ vf, const float* __restrict__ bfp,
    float* __restrict__ outp)
{
    const int b    = blockIdx.y;
    const int k0   = blockIdx.x * 64;
    const int tid  = threadIdx.x;
    const int wave = tid >> 6;
    const int lane = tid & 63;
    const int quad = lane >> 4;
    const int col  = lane & 15;

    __shared__ float sl[8][64];
    __shared__ float wcol[64];

    bf16x8 kf[4][2];
    {
        const ushort* Kbase = Kb + ((size_t)(b * SEQ + k0)) * DIM;
        #pragma unroll
        for (int t = 0; t < 4; ++t)
            #pragma unroll
            for (int c = 0; c < 2; ++c)
                kf[t][c] = *(const bf16x8*)(Kbase + (size_t)(t * 16 + col) * DIM + quad * 8 + c * 32);
    }

    const ushort* Qstart = Qb + ((size_t)(b * SEQ + wave * 256 + col)) * DIM + quad * 8;

    // ---- Phase A: column sums ----
    float l[4][4] = {};
    {
        const ushort* Qrow = Qstart;
        for (int qi = 0; qi < 16; ++qi) {
            bf16x8 q0 = *(const bf16x8*)(Qrow);
            bf16x8 q1 = *(const bf16x8*)(Qrow + 32);
            Qrow += 16 * DIM;
            #pragma unroll
            for (int t = 0; t < 4; ++t) {
                f32x4 acc = {0.f, 0.f, 0.f, 0.f};
                acc = __builtin_amdgcn_mfma_f32_16x16x32_bf16(kf[t][0], q0, acc, 0, 0, 0);
                acc = __builtin_amdgcn_mfma_f32_16x16x32_bf16(kf[t][1], q1, acc, 0, 0, 0);
                #pragma unroll
                for (int r = 0; r < 4; ++r)
                    l[t][r] += fast_exp2(acc[r]);
            }
        }
    }
    #pragma unroll
    for (int t = 0; t < 4; ++t)
        #pragma unroll
        for (int r = 0; r < 4; ++r) {
            float v = l[t][r];
            v += __shfl_xor(v, 1); v += __shfl_xor(v, 2);
            v += __shfl_xor(v, 4); v += __shfl_xor(v, 8);
            l[t][r] = v;
        }
    if (col == 0) {
        #pragma unroll
        for (int t = 0; t < 4; ++t)
            #pragma unroll
            for (int r = 0; r < 4; ++r)
                sl[wave][t * 16 + quad * 4 + r] = l[t][r];
    }
    __syncthreads();
    if (tid < 64) {
        float ll = 0.f;
        #pragma unroll
        for (int w = 0; w < 8; ++w) ll += sl[w][tid];
        wcol[tid] = vf[(size_t)b * SEQ + k0 + tid] / ll;
    }
    __syncthreads();

    // ---- Phase B: per-q accumulate over k ----
    float wreg[4][4];
    #pragma unroll
    for (int t = 0; t < 4; ++t)
        #pragma unroll
        for (int r = 0; r < 4; ++r)
            wreg[t][r] = wcol[t * 16 + quad * 4 + r];

    const float bias = bfp[0] * (1.0f / (SEQ / 64));   // each block adds bf/32
    float* outb = outp + (size_t)b * SEQ;
    {
        const ushort* Qrow = Qstart;
        for (int qi = 0; qi < 16; ++qi) {
            bf16x8 q0 = *(const bf16x8*)(Qrow);
            bf16x8 q1 = *(const bf16x8*)(Qrow + 32);
            Qrow += 16 * DIM;
            float rs = 0.f;
            #pragma unroll
            for (int t = 0; t < 4; ++t) {
                f32x4 acc = {0.f, 0.f, 0.f, 0.f};
                acc = __builtin_amdgcn_mfma_f32_16x16x32_bf16(kf[t][0], q0, acc, 0, 0, 0);
                acc = __builtin_amdgcn_mfma_f32_16x16x32_bf16(kf[t][1], q1, acc, 0, 0, 0);
                #pragma unroll
                for (int r = 0; r < 4; ++r)
                    rs += fast_exp2(acc[r]) * wreg[t][r];
            }
            rs += __shfl_xor(rs, 16);
            rs += __shfl_xor(rs, 32);
            if (quad == 0)
                atomicAdd(&outb[wave * 256 + qi * 16 + col], rs + bias);
        }
    }
}

// ---------------------------------------------------------------------------
extern "C" void kernel_launch(void* const* d_in, const int* in_sizes, int n_in,
                              void* d_out, int out_size, void* d_ws, size_t ws_size,
                              hipStream_t stream) {
    (void)in_sizes; (void)n_in; (void)ws_size;
    const float* x  = (const float*)d_in[0];
    const float* Wq = (const float*)d_in[1];
    const float* Wk = (const float*)d_in[2];
    const float* Wv = (const float*)d_in[3];
    const float* Wf = (const float*)d_in[4];
    const float* bf = (const float*)d_in[5];
    float* outp = (float*)d_out;

    float*  wvf = (float*)d_ws;                                  // 256 floats
    float*  vf  = wvf + 256;                                     // B*S
    float*  pet = vf + (size_t)BATCH * SEQ;                      // SEQ*HID
    ushort* Wt  = (ushort*)(pet + (size_t)SEQ * HID);            // 128*128
    ushort* Qb  = Wt + 128 * 128;                                // B*S*D bf16
    ushort* Kb  = Qb + (size_t)BATCH * SEQ * DIM;                // B*S*D bf16

    hipMemsetAsync(d_out, 0, (size_t)out_size * sizeof(float), stream);
    k_peprep<<<SEQ * (HID / 2) / 256, 256, 0, stream>>>(Wq, Wk, Wv, Wf, pet, Wt, wvf);
    k_qkv<<<BATCH * SEQ / 64, 512, 0, stream>>>(x, pet, Wt, wvf, Qb, Kb, vf);
    k_attn<<<dim3(SEQ / 64, BATCH), 512, 0, stream>>>(Qb, Kb, vf, bf, outp);
}